// Round 5
// baseline (799.993 us; speedup 1.0000x reference)
//
#include <hip/hip_runtime.h>
#include <hip/hip_bf16.h>
#include <math.h>

#define HH 32
#define NODE_IN 64
#define EDGE_IN 16
#define EDGE_H 128
#define M_TILE 64   // edges per block in MFMA edge kernel (4 waves x 16 edges)

typedef __attribute__((ext_vector_type(8))) short bf16x8;
typedef __attribute__((ext_vector_type(4))) float f32x4;

__device__ inline unsigned short f2bf(float f) {
    union { float f; unsigned int u; } v; v.f = f;
    unsigned int r = v.u + 0x7fff + ((v.u >> 16) & 1);   // RNE (inputs never NaN)
    return (unsigned short)(r >> 16);
}

// ---------------- prep: W2 f32 -> bf16, linear layout ----------------
__global__ void k_prep_w2(const float* __restrict__ en2_w, unsigned short* __restrict__ W2b) {
    int i = blockIdx.x * 256 + threadIdx.x;
    W2b[i] = f2bf(en2_w[i]);
}

// ---------------- prep: R = relu(e_feat @ en1_w^T + en1_b) -> bf16 [E_pad][128] ----------------
// One edge per thread; w1 LDS reads are wave-UNIFORM -> broadcast, zero conflicts.
__global__ void k_prep_r(const float* __restrict__ e_feat, const float* __restrict__ en1_w,
                         const float* __restrict__ en1_b, unsigned short* __restrict__ Rb,
                         int E, int E_pad) {
    __shared__ float w1_s[EDGE_H][EDGE_IN];   // [j][k] — indexed uniformly across the wave
    __shared__ float b1_s[EDGE_H];
    int t = threadIdx.x;
    for (int i = t; i < EDGE_H * EDGE_IN; i += 256) w1_s[i >> 4][i & 15] = en1_w[i];
    for (int i = t; i < EDGE_H; i += 256) b1_s[i] = en1_b[i];
    __syncthreads();
    int e = blockIdx.x * 256 + t;
    if (e >= E_pad) return;
    float ef[EDGE_IN];
    if (e < E) {
        #pragma unroll
        for (int q = 0; q < 4; ++q) {
            float4 v = ((const float4*)(e_feat + (size_t)e * EDGE_IN))[q];
            ef[q * 4 + 0] = v.x; ef[q * 4 + 1] = v.y; ef[q * 4 + 2] = v.z; ef[q * 4 + 3] = v.w;
        }
    } else {
        #pragma unroll
        for (int k = 0; k < EDGE_IN; ++k) ef[k] = 0.f;   // zero-pad rows
    }
    #pragma unroll 2
    for (int j8 = 0; j8 < 16; ++j8) {
        unsigned short rr[8];
        #pragma unroll
        for (int jj = 0; jj < 8; ++jj) {
            int j = j8 * 8 + jj;
            float acc = b1_s[j];
            #pragma unroll
            for (int k = 0; k < EDGE_IN; ++k) acc += ef[k] * w1_s[j][k];
            rr[jj] = f2bf(fmaxf(acc, 0.f));
        }
        *(uint4*)(Rb + (size_t)e * EDGE_H + j8 * 8) = *(const uint4*)rr;
    }
}

// ---------------- lin0 ----------------
__global__ void k_lin0(const float* __restrict__ nf, const float* __restrict__ w,
                       const float* __restrict__ b, float* __restrict__ out,
                       float* __restrict__ h0, int n) {
    __shared__ float nf_s[8][NODE_IN];
    __shared__ float w_s[HH][NODE_IN + 1];
    int t = threadIdx.x;
    for (int i = t; i < HH * NODE_IN; i += 256) w_s[i / NODE_IN][i % NODE_IN] = w[i];
    int n0 = blockIdx.x * 8;
    for (int i = t; i < 8 * NODE_IN; i += 256) {
        int nl = i / NODE_IN, k = i % NODE_IN;
        int nn = n0 + nl;
        nf_s[nl][k] = (nn < n) ? nf[(size_t)nn * NODE_IN + k] : 0.f;
    }
    __syncthreads();
    int nl = t >> 5, h = t & 31;
    int nn = n0 + nl;
    if (nn < n) {
        float acc = b[h];
        #pragma unroll
        for (int k = 0; k < NODE_IN; ++k) acc += nf_s[nl][k] * w_s[h][k];
        acc = fmaxf(acc, 0.f);
        out[(size_t)nn * HH + h] = acc;
        h0[(size_t)nn * HH + h] = acc;
    }
}

// ---------------- CSR build (by dst) ----------------
__global__ void k_zero_int(int* __restrict__ p, int n) {
    int i = blockIdx.x * 256 + threadIdx.x;
    if (i < n) p[i] = 0;
}
__global__ void k_hist(const int* __restrict__ dst, int* __restrict__ deg, int E) {
    int e = blockIdx.x * 256 + threadIdx.x;
    if (e < E) atomicAdd(&deg[dst[e]], 1);
}
__global__ void k_scan1(const int* __restrict__ deg, int* __restrict__ offtmp,
                        int* __restrict__ bsum, int n) {
    __shared__ int sh[256];
    int tid = threadIdx.x;
    int i = blockIdx.x * 256 + tid;
    int v = (i < n) ? deg[i] : 0;
    sh[tid] = v;
    __syncthreads();
    for (int d = 1; d < 256; d <<= 1) {
        int add = (tid >= d) ? sh[tid - d] : 0;
        __syncthreads();
        sh[tid] += add;
        __syncthreads();
    }
    if (i < n) offtmp[i] = sh[tid] - v;
    if (tid == 255) bsum[blockIdx.x] = sh[255];
}
__global__ void k_scan2(int* __restrict__ bsum, int nb) {
    __shared__ int sh[256];
    int tid = threadIdx.x;
    int v = (tid < nb) ? bsum[tid] : 0;
    sh[tid] = v;
    __syncthreads();
    for (int d = 1; d < 256; d <<= 1) {
        int add = (tid >= d) ? sh[tid - d] : 0;
        __syncthreads();
        sh[tid] += add;
        __syncthreads();
    }
    if (tid < nb) bsum[tid] = sh[tid] - v;
}
__global__ void k_scan3(const int* __restrict__ offtmp, const int* __restrict__ bsum,
                        int* __restrict__ offsets, int* __restrict__ cursor, int n, int E) {
    int i = blockIdx.x * 256 + threadIdx.x;
    if (i < n) { offsets[i] = offtmp[i] + bsum[i >> 8]; cursor[i] = 0; }
    if (i == n) offsets[n] = E;
}
__global__ void k_scatter_pos(const int* __restrict__ dst, const int* __restrict__ offsets,
                              int* __restrict__ cursor, int* __restrict__ pos, int E) {
    int e = blockIdx.x * 256 + threadIdx.x;
    if (e < E) pos[e] = offsets[dst[e]] + atomicAdd(&cursor[dst[e]], 1);
}

// ---------------- MFMA edge kernel v3: 4 waves x 16 edges, B from L2, no inner barriers ----------------
__global__ void __launch_bounds__(256, 4)
k_edge_mfma3(const unsigned short* __restrict__ Rb, const unsigned short* __restrict__ W2b,
             const float* __restrict__ b2, const float* __restrict__ cur,
             const int* __restrict__ src, const int* __restrict__ pos,
             float* __restrict__ outp, int E) {
    __shared__ float x_t[HH][68];     // x transposed [h][edge-in-block]
    __shared__ float b2_s[HH * HH];
    int t = threadIdx.x, wave = t >> 6, l = t & 63;
    int lo = l & 15, lq = l >> 4;
    int e0 = blockIdx.x * M_TILE;

    for (int i = t; i < HH * HH; i += 256) b2_s[i] = b2[i];

    // gather x[e][:] = cur[src[e]][:], transposed into LDS (8 lanes per edge)
    for (int i = t; i < M_TILE * 8; i += 256) {
        int el = i >> 3, c = i & 7;
        int e = e0 + el;
        float4 v = make_float4(0.f, 0.f, 0.f, 0.f);
        if (e < E) v = ((const float4*)(cur + (size_t)src[e] * HH))[c];
        x_t[c * 4 + 0][el] = v.x; x_t[c * 4 + 1][el] = v.y;
        x_t[c * 4 + 2][el] = v.z; x_t[c * 4 + 3][el] = v.w;
    }

    // A fragments: this wave's 16 edge-rows, all K=128 (16 VGPR, live across loop)
    bf16x8 afrag[4];
    #pragma unroll
    for (int ks = 0; ks < 4; ++ks)
        afrag[ks] = *(const bf16x8*)(Rb + (size_t)(e0 + wave * 16 + lo) * EDGE_H + ks * 32 + lq * 8);

    __syncthreads();

    float macc[2][4];
    #pragma unroll
    for (int nn = 0; nn < 2; ++nn)
        #pragma unroll
        for (int r = 0; r < 4; ++r) macc[nn][r] = 0.f;

    #pragma unroll 2
    for (int h = 0; h < HH; ++h) {
        // B fragments straight from global (L2-resident 256 KB, shared by all blocks)
        bf16x8 bfrag[2][4];
        #pragma unroll
        for (int nn = 0; nn < 2; ++nn)
            #pragma unroll
            for (int ks = 0; ks < 4; ++ks)
                bfrag[nn][ks] = *(const bf16x8*)(W2b + (size_t)(h * HH + nn * 16 + lo) * EDGE_H + ks * 32 + lq * 8);

        // acc starts at b2 (MFMA C-in is free) => D = R·W2^T + b2
        f32x4 acc[2];
        #pragma unroll
        for (int nn = 0; nn < 2; ++nn) {
            float bb = b2_s[h * HH + nn * 16 + lo];
            acc[nn] = (f32x4){bb, bb, bb, bb};
        }
        #pragma unroll
        for (int ks = 0; ks < 4; ++ks)
            #pragma unroll
            for (int nn = 0; nn < 2; ++nn)
                acc[nn] = __builtin_amdgcn_mfma_f32_16x16x32_bf16(
                    afrag[ks], bfrag[nn][ks], acc[nn], 0, 0, 0);

        const float4 xv = *(const float4*)&x_t[h][wave * 16 + lq * 4];
        macc[0][0] += xv.x * acc[0][0];
        macc[0][1] += xv.y * acc[0][1];
        macc[0][2] += xv.z * acc[0][2];
        macc[0][3] += xv.w * acc[0][3];
        macc[1][0] += xv.x * acc[1][0];
        macc[1][1] += xv.y * acc[1][1];
        macc[1][2] += xv.z * acc[1][2];
        macc[1][3] += xv.w * acc[1][3];
    }

    // store: edge rows wave*16 + lq*4 + r, cols nn*16+lo (16-lane contiguous)
    int ebase = e0 + wave * 16 + lq * 4;
    const int4 p4 = *(const int4*)&pos[ebase];
    int pr[4] = { p4.x, p4.y, p4.z, p4.w };
    #pragma unroll
    for (int r = 0; r < 4; ++r) {
        if (ebase + r < E) {
            outp[(size_t)pr[r] * HH + lo]      = macc[0][r];
            outp[(size_t)pr[r] * HH + 16 + lo] = macc[1][r];
        }
    }
}

// ---------------- node update: CSR gather-sum + conv/residual/lin1/relu ----------------
__global__ void k_node_update(const float* __restrict__ msg_sorted, const int* __restrict__ offsets,
                              const float* __restrict__ cur, const float* __restrict__ h0,
                              const float* __restrict__ conv_bias,
                              const float* __restrict__ lin1_w, const float* __restrict__ lin1_b,
                              float* __restrict__ nxt, int n) {
    __shared__ float t_s[8][HH + 1];
    __shared__ float w_s[HH][HH + 1];
    int t = threadIdx.x;
    for (int i = t; i < HH * HH; i += 256) w_s[i >> 5][i & 31] = lin1_w[i];
    int nl = t >> 5, h = t & 31;
    int nn = blockIdx.x * 8 + nl;
    float tv = 0.f;
    if (nn < n) {
        int s0 = offsets[nn], s1 = offsets[nn + 1];
        float s = 0.f;
        for (int i = s0; i < s1; ++i) s += msg_sorted[(size_t)i * HH + h];
        size_t idx = (size_t)nn * HH + h;
        float conv = s + cur[idx] + conv_bias[h];
        tv = 0.5f * conv + 0.5f * h0[idx];
    }
    t_s[nl][h] = tv;
    __syncthreads();
    if (nn < n) {
        const float BETA = 1.0f / 3.0f;
        float d = lin1_b[h];
        #pragma unroll
        for (int k = 0; k < HH; ++k) d += t_s[nl][k] * w_s[h][k];
        float v = BETA * d + (1.0f - BETA) * tv;
        nxt[(size_t)nn * HH + h] = fmaxf(v, 0.f);
    }
}

// ---------------- BN batch statistics ----------------
__global__ void k_bn_stats(const float* __restrict__ out, float* __restrict__ stats, int n) {
    int t = threadIdx.x;
    int h = t & 31, rg = t >> 5;
    float s = 0.f, s2 = 0.f;
    for (int nn = blockIdx.x * 8 + rg; nn < n; nn += gridDim.x * 8) {
        float v = out[(size_t)nn * HH + h];
        s += v; s2 += v * v;
    }
    __shared__ float sh[256], sh2[256];
    sh[t] = s; sh2[t] = s2;
    __syncthreads();
    if (rg == 0) {
        #pragma unroll
        for (int g = 1; g < 8; ++g) { s += sh[g * 32 + h]; s2 += sh2[g * 32 + h]; }
        atomicAdd(&stats[h], s);
        atomicAdd(&stats[32 + h], s2);
    }
}

// ---------------- BN apply + y_sigmoid head ----------------
__global__ void k_node_out(const float* __restrict__ out, const float* __restrict__ stats,
                           const float* __restrict__ gamma, const float* __restrict__ beta,
                           const float* __restrict__ ylin_w, const float* __restrict__ ylin_b,
                           float* __restrict__ y_bn, float* __restrict__ y_sig, int n) {
    int nn = blockIdx.x * blockDim.x + threadIdx.x;
    if (nn >= n) return;
    float inv_n = 1.f / (float)n;
    float yb[HH];
    #pragma unroll
    for (int h = 0; h < HH; ++h) {
        float mu = stats[h] * inv_n;
        float var = stats[32 + h] * inv_n - mu * mu;
        float v = out[(size_t)nn * HH + h];
        yb[h] = (v - mu) * rsqrtf(var + 1e-5f) * gamma[h] + beta[h];
    }
    #pragma unroll
    for (int h = 0; h < HH; ++h) y_bn[(size_t)nn * HH + h] = yb[h];
    #pragma unroll
    for (int c = 0; c < 3; ++c) {
        float d = ylin_b[c];
        #pragma unroll
        for (int h = 0; h < HH; ++h) d += yb[h] * ylin_w[c * HH + h];
        y_sig[(size_t)nn * 3 + c] = 1.f / (1.f + expf(-d));
    }
}

// ---------------- edge-hop head ----------------
__global__ void k_edge_hop(const float* __restrict__ y_bn, const int* __restrict__ sl,
                           const int* __restrict__ dl, const float* __restrict__ w,
                           const float* __restrict__ b, float* __restrict__ outp, int e2) {
    int e = blockIdx.x * blockDim.x + threadIdx.x;
    if (e >= e2) return;
    const float4* a = (const float4*)(y_bn + (size_t)sl[e] * HH);
    const float4* c = (const float4*)(y_bn + (size_t)dl[e] * HH);
    float d = b[0];
    #pragma unroll
    for (int q = 0; q < 8; ++q) {
        float4 av = a[q], cv = c[q];
        float4 wv = ((const float4*)w)[q];
        d += av.x * cv.x * wv.x + av.y * cv.y * wv.y + av.z * cv.z * wv.z + av.w * cv.w * wv.w;
    }
    outp[e] = 1.f / (1.f + expf(-d));
}

extern "C" void kernel_launch(void* const* d_in, const int* in_sizes, int n_in,
                              void* d_out, int out_size, void* d_ws, size_t ws_size,
                              hipStream_t stream) {
    const float* n_feat   = (const float*)d_in[0];
    const float* e_feat   = (const float*)d_in[1];
    const int*   src      = (const int*)d_in[2];
    const int*   dst      = (const int*)d_in[3];
    const int*   src_list = (const int*)d_in[4];
    const int*   dst_list = (const int*)d_in[5];
    const float* lin0_w   = (const float*)d_in[6];
    const float* lin0_b   = (const float*)d_in[7];
    const float* en1_w    = (const float*)d_in[8];
    const float* en1_b    = (const float*)d_in[9];
    const float* en2_w    = (const float*)d_in[10];
    const float* en2_b    = (const float*)d_in[11];
    const float* conv_bias= (const float*)d_in[12];
    const float* lin1_w   = (const float*)d_in[13];
    const float* lin1_b   = (const float*)d_in[14];
    const float* bn_gamma = (const float*)d_in[15];
    const float* bn_beta  = (const float*)d_in[16];
    const float* ylin_w   = (const float*)d_in[17];
    const float* ylin_b   = (const float*)d_in[18];
    const float* ylin2_w  = (const float*)d_in[19];
    const float* ylin2_b  = (const float*)d_in[20];

    int n  = in_sizes[0] / NODE_IN;
    int E  = in_sizes[1] / EDGE_IN;
    int e2 = in_sizes[4];
    int E_pad = (E + M_TILE - 1) & ~(M_TILE - 1);

    float* ws    = (float*)d_ws;
    size_t nh    = (size_t)n * HH;
    float* out_a = ws;
    float* out_b = out_a + nh;
    float* h0    = out_b + nh;
    float* y_bn  = h0 + nh;
    float* stats = y_bn + nh;                               // 64 floats
    float* msg_sorted = stats + 64;                         // E_pad*32 f32
    unsigned short* W2b = (unsigned short*)(msg_sorted + (size_t)E_pad * HH);  // 1024*128 bf16
    unsigned short* Rb  = W2b + 1024 * EDGE_H;              // E_pad*128 bf16
    int* ibase   = (int*)(Rb + (size_t)E_pad * EDGE_H);
    int* deg     = ibase;            // n
    int* offtmp  = deg + n;          // n
    int* bsum    = offtmp + n;       // <=256
    int* offsets = bsum + 256;       // n+1
    int* cursor  = offsets + n + 1;  // n
    int* pos     = cursor + n;       // E_pad (tail garbage; stores guarded)

    int nb = (n + 255) / 256;

    k_prep_w2<<<(1024 * EDGE_H) / 256, 256, 0, stream>>>(en2_w, W2b);
    k_prep_r<<<(E_pad + 255) / 256, 256, 0, stream>>>(e_feat, en1_w, en1_b, Rb, E, E_pad);
    k_lin0<<<(n + 7) / 8, 256, 0, stream>>>(n_feat, lin0_w, lin0_b, out_a, h0, n);

    // CSR by dst
    k_zero_int<<<nb, 256, 0, stream>>>(deg, n);
    k_hist<<<(E + 255) / 256, 256, 0, stream>>>(dst, deg, E);
    k_scan1<<<nb, 256, 0, stream>>>(deg, offtmp, bsum, n);
    k_scan2<<<1, 256, 0, stream>>>(bsum, nb);
    k_scan3<<<(n + 256) / 256, 256, 0, stream>>>(offtmp, bsum, offsets, cursor, n, E);
    k_scatter_pos<<<(E + 255) / 256, 256, 0, stream>>>(dst, offsets, cursor, pos, E);

    const float* cur = out_a;
    float* nxt = out_b;
    for (int s = 0; s < 3; ++s) {
        k_edge_mfma3<<<E_pad / M_TILE, 256, 0, stream>>>(
            Rb, W2b, en2_b, cur, src, pos, msg_sorted, E);
        k_node_update<<<(n + 7) / 8, 256, 0, stream>>>(
            msg_sorted, offsets, cur, h0, conv_bias, lin1_w, lin1_b, nxt, n);
        float* t = (float*)cur; cur = nxt; nxt = t;
    }

    hipMemsetAsync(stats, 0, 64 * sizeof(float), stream);
    k_bn_stats<<<256, 256, 0, stream>>>(cur, stats, n);

    float* y_sig = (float*)d_out;
    float* e_out = y_sig + (size_t)n * 3;
    k_node_out<<<(n + 255) / 256, 256, 0, stream>>>(
        cur, stats, bn_gamma, bn_beta, ylin_w, ylin_b, y_bn, y_sig, n);
    k_edge_hop<<<(e2 + 255) / 256, 256, 0, stream>>>(
        y_bn, src_list, dst_list, ylin2_w, ylin2_b, e_out, e2);
}

// Round 6
// 322.136 us; speedup vs baseline: 2.4834x; 2.4834x over previous
//
#include <hip/hip_runtime.h>
#include <hip/hip_bf16.h>
#include <math.h>

#define HH 32
#define NODE_IN 64
#define EDGE_IN 16
#define EDGE_H 128
#define M_TILE 256   // edges per block in MFMA edge kernel (8 waves x 32 edges)

typedef __attribute__((ext_vector_type(8))) short bf16x8;
typedef __attribute__((ext_vector_type(4))) float f32x4;

__device__ inline unsigned short f2bf(float f) {
    union { float f; unsigned int u; } v; v.f = f;
    unsigned int r = v.u + 0x7fff + ((v.u >> 16) & 1);   // RNE (inputs never NaN)
    return (unsigned short)(r >> 16);
}

__device__ inline void gload_lds16(const void* g, void* lds) {
    __builtin_amdgcn_global_load_lds(
        (const __attribute__((address_space(1))) void*)g,
        (__attribute__((address_space(3))) void*)lds, 16, 0, 0);
}

// ---------------- prep: W2 f32 -> bf16, CHUNK-SWIZZLED global layout ----------------
// W2s[c*128 + p*8 + sub] = bf16(en2_w[c*128 + (p^(c&15))*8 + sub])
// Linear global_load_lds of a 32-col slice lands swizzled in LDS; ds_read_b128
// at chunk (ks*4+lq)^lo is ~2-way bank-conflict (free).
__global__ void k_prep_w2(const float* __restrict__ en2_w, unsigned short* __restrict__ W2s) {
    int i = blockIdx.x * 256 + threadIdx.x;
    int r = i >> 7, q = i & 127;
    int p = q >> 3, sub = q & 7;
    int c = p ^ (r & 15);
    W2s[i] = f2bf(en2_w[r * EDGE_H + c * 8 + sub]);
}

// ---------------- prep: R = relu(e_feat @ en1_w^T + en1_b) -> bf16 [E_pad][128] ----------------
// One edge per thread; w1 LDS reads are wave-UNIFORM -> broadcast, zero conflicts.
__global__ void k_prep_r(const float* __restrict__ e_feat, const float* __restrict__ en1_w,
                         const float* __restrict__ en1_b, unsigned short* __restrict__ Rb,
                         int E, int E_pad) {
    __shared__ float w1_s[EDGE_H][EDGE_IN];
    __shared__ float b1_s[EDGE_H];
    int t = threadIdx.x;
    for (int i = t; i < EDGE_H * EDGE_IN; i += 256) w1_s[i >> 4][i & 15] = en1_w[i];
    for (int i = t; i < EDGE_H; i += 256) b1_s[i] = en1_b[i];
    __syncthreads();
    int e = blockIdx.x * 256 + t;
    if (e >= E_pad) return;
    float ef[EDGE_IN];
    if (e < E) {
        #pragma unroll
        for (int q = 0; q < 4; ++q) {
            float4 v = ((const float4*)(e_feat + (size_t)e * EDGE_IN))[q];
            ef[q * 4 + 0] = v.x; ef[q * 4 + 1] = v.y; ef[q * 4 + 2] = v.z; ef[q * 4 + 3] = v.w;
        }
    } else {
        #pragma unroll
        for (int k = 0; k < EDGE_IN; ++k) ef[k] = 0.f;
    }
    #pragma unroll 2
    for (int j8 = 0; j8 < 16; ++j8) {
        unsigned short rr[8];
        #pragma unroll
        for (int jj = 0; jj < 8; ++jj) {
            int j = j8 * 8 + jj;
            float acc = b1_s[j];
            #pragma unroll
            for (int k = 0; k < EDGE_IN; ++k) acc += ef[k] * w1_s[j][k];
            rr[jj] = f2bf(fmaxf(acc, 0.f));
        }
        *(uint4*)(Rb + (size_t)e * EDGE_H + j8 * 8) = *(const uint4*)rr;
    }
}

// ---------------- lin0 ----------------
__global__ void k_lin0(const float* __restrict__ nf, const float* __restrict__ w,
                       const float* __restrict__ b, float* __restrict__ out,
                       float* __restrict__ h0, int n) {
    __shared__ float nf_s[8][NODE_IN];
    __shared__ float w_s[HH][NODE_IN + 1];
    int t = threadIdx.x;
    for (int i = t; i < HH * NODE_IN; i += 256) w_s[i / NODE_IN][i % NODE_IN] = w[i];
    int n0 = blockIdx.x * 8;
    for (int i = t; i < 8 * NODE_IN; i += 256) {
        int nl = i / NODE_IN, k = i % NODE_IN;
        int nn = n0 + nl;
        nf_s[nl][k] = (nn < n) ? nf[(size_t)nn * NODE_IN + k] : 0.f;
    }
    __syncthreads();
    int nl = t >> 5, h = t & 31;
    int nn = n0 + nl;
    if (nn < n) {
        float acc = b[h];
        #pragma unroll
        for (int k = 0; k < NODE_IN; ++k) acc += nf_s[nl][k] * w_s[h][k];
        acc = fmaxf(acc, 0.f);
        out[(size_t)nn * HH + h] = acc;
        h0[(size_t)nn * HH + h] = acc;
    }
}

// ---------------- CSR build (by dst) ----------------
__global__ void k_zero_int(int* __restrict__ p, int n) {
    int i = blockIdx.x * 256 + threadIdx.x;
    if (i < n) p[i] = 0;
}
__global__ void k_hist(const int* __restrict__ dst, int* __restrict__ deg, int E) {
    int e = blockIdx.x * 256 + threadIdx.x;
    if (e < E) atomicAdd(&deg[dst[e]], 1);
}
__global__ void k_scan1(const int* __restrict__ deg, int* __restrict__ offtmp,
                        int* __restrict__ bsum, int n) {
    __shared__ int sh[256];
    int tid = threadIdx.x;
    int i = blockIdx.x * 256 + tid;
    int v = (i < n) ? deg[i] : 0;
    sh[tid] = v;
    __syncthreads();
    for (int d = 1; d < 256; d <<= 1) {
        int add = (tid >= d) ? sh[tid - d] : 0;
        __syncthreads();
        sh[tid] += add;
        __syncthreads();
    }
    if (i < n) offtmp[i] = sh[tid] - v;
    if (tid == 255) bsum[blockIdx.x] = sh[255];
}
__global__ void k_scan2(int* __restrict__ bsum, int nb) {
    __shared__ int sh[256];
    int tid = threadIdx.x;
    int v = (tid < nb) ? bsum[tid] : 0;
    sh[tid] = v;
    __syncthreads();
    for (int d = 1; d < 256; d <<= 1) {
        int add = (tid >= d) ? sh[tid - d] : 0;
        __syncthreads();
        sh[tid] += add;
        __syncthreads();
    }
    if (tid < nb) bsum[tid] = sh[tid] - v;
}
__global__ void k_scan3(const int* __restrict__ offtmp, const int* __restrict__ bsum,
                        int* __restrict__ offsets, int* __restrict__ cursor, int n, int E) {
    int i = blockIdx.x * 256 + threadIdx.x;
    if (i < n) { offsets[i] = offtmp[i] + bsum[i >> 8]; cursor[i] = 0; }
    if (i == n) offsets[n] = E;
}
__global__ void k_scatter_pos(const int* __restrict__ dst, const int* __restrict__ offsets,
                              int* __restrict__ cursor, int* __restrict__ pos, int E) {
    int e = blockIdx.x * 256 + threadIdx.x;
    if (e < E) pos[e] = offsets[dst[e]] + atomicAdd(&cursor[dst[e]], 1);
}

// ---------------- MFMA edge kernel v4 ----------------
// 8 waves x 32 edges; W2 staged per-h-slice (8KB) in a 4-deep LDS ring via
// global_load_lds; depth-3 prefetch, counted vmcnt(2), raw s_barrier (1/iter).
__global__ void __launch_bounds__(512, 2)
k_edge_mfma4(const unsigned short* __restrict__ Rb, const unsigned short* __restrict__ W2s,
             const float* __restrict__ b2, const float* __restrict__ cur,
             const int* __restrict__ src, const int* __restrict__ pos,
             float* __restrict__ outp, int E) {
    __shared__ unsigned short w2buf[4][32 * EDGE_H];  // 4 x 8KB ring
    __shared__ float x_t[HH][M_TILE];                 // x transposed [h][edge]
    __shared__ float b2_s[HH * HH];
    int t = threadIdx.x, wave = t >> 6, l = t & 63;
    int lo = l & 15, lq = l >> 4;
    int e0 = blockIdx.x * M_TILE;

    for (int i = t; i < HH * HH; i += 512) b2_s[i] = b2[i];

    // gather x[e][:] = cur[src[e]][:], transposed into LDS (8 lanes per edge)
    for (int i = t; i < M_TILE * 8; i += 512) {
        int el = i >> 3, c = i & 7;
        int e = e0 + el;
        float4 v = make_float4(0.f, 0.f, 0.f, 0.f);
        if (e < E) v = ((const float4*)(cur + (size_t)src[e] * HH))[c];
        x_t[c * 4 + 0][el] = v.x; x_t[c * 4 + 1][el] = v.y;
        x_t[c * 4 + 2][el] = v.z; x_t[c * 4 + 3][el] = v.w;
    }

    // A fragments: this wave's 32 edge-rows (2 m-tiles), all K=128
    bf16x8 afrag[2][4];
    #pragma unroll
    for (int m = 0; m < 2; ++m)
        #pragma unroll
        for (int ks = 0; ks < 4; ++ks)
            afrag[m][ks] = *(const bf16x8*)(Rb + (size_t)(e0 + wave * 32 + m * 16 + lo) * EDGE_H + ks * 32 + lq * 8);

    // prologue: stage slices 0,1,2 (1 gload_lds per thread per slice)
    #pragma unroll
    for (int s = 0; s < 3; ++s)
        gload_lds16(W2s + (size_t)s * 4096 + t * 8, &w2buf[s][t * 8]);

    // this wave's x_t/b2 ds_writes must be visible after the first barrier
    asm volatile("s_waitcnt lgkmcnt(0)" ::: "memory");

    float macc[2][2][4];
    #pragma unroll
    for (int m = 0; m < 2; ++m)
        #pragma unroll
        for (int nn = 0; nn < 2; ++nn)
            #pragma unroll
            for (int r = 0; r < 4; ++r) macc[m][nn][r] = 0.f;

    #pragma unroll 4
    for (int h = 0; h < HH; ++h) {
        // wait for slice h (2 newer slices may stay in flight), then sync
        if (h < 30)      asm volatile("s_waitcnt vmcnt(2)" ::: "memory");
        else if (h == 30) asm volatile("s_waitcnt vmcnt(1)" ::: "memory");
        else              asm volatile("s_waitcnt vmcnt(0)" ::: "memory");
        __builtin_amdgcn_s_barrier();
        // everyone is past compute(h-1): safe to overwrite ring slot (h+3)&3
        if (h + 3 < HH)
            gload_lds16(W2s + (size_t)(h + 3) * 4096 + t * 8, &w2buf[(h + 3) & 3][t * 8]);

        const unsigned short* wb = w2buf[h & 3];
        bf16x8 bfrag[2][4];
        #pragma unroll
        for (int nn = 0; nn < 2; ++nn)
            #pragma unroll
            for (int ks = 0; ks < 4; ++ks)
                bfrag[nn][ks] = *(const bf16x8*)&wb[(nn * 16 + lo) * EDGE_H + (((ks * 4 + lq) ^ lo) * 8)];

        f32x4 acc[2][2];
        #pragma unroll
        for (int nn = 0; nn < 2; ++nn) {
            float bb = b2_s[h * HH + nn * 16 + lo];
            acc[0][nn] = (f32x4){bb, bb, bb, bb};
            acc[1][nn] = (f32x4){bb, bb, bb, bb};
        }
        #pragma unroll
        for (int ks = 0; ks < 4; ++ks)
            #pragma unroll
            for (int m = 0; m < 2; ++m)
                #pragma unroll
                for (int nn = 0; nn < 2; ++nn)
                    acc[m][nn] = __builtin_amdgcn_mfma_f32_16x16x32_bf16(
                        afrag[m][ks], bfrag[nn][ks], acc[m][nn], 0, 0, 0);

        #pragma unroll
        for (int m = 0; m < 2; ++m) {
            const float4 xv = *(const float4*)&x_t[h][wave * 32 + m * 16 + lq * 4];
            #pragma unroll
            for (int nn = 0; nn < 2; ++nn) {
                macc[m][nn][0] += xv.x * acc[m][nn][0];
                macc[m][nn][1] += xv.y * acc[m][nn][1];
                macc[m][nn][2] += xv.z * acc[m][nn][2];
                macc[m][nn][3] += xv.w * acc[m][nn][3];
            }
        }
    }

    // store: edge rows wave*32 + m*16 + lq*4 + r, cols nn*16+lo
    #pragma unroll
    for (int m = 0; m < 2; ++m) {
        int ebase = e0 + wave * 32 + m * 16 + lq * 4;
        const int4 p4 = *(const int4*)&pos[ebase];
        int pr[4] = { p4.x, p4.y, p4.z, p4.w };
        #pragma unroll
        for (int r = 0; r < 4; ++r) {
            if (ebase + r < E) {
                outp[(size_t)pr[r] * HH + lo]      = macc[m][0][r];
                outp[(size_t)pr[r] * HH + 16 + lo] = macc[m][1][r];
            }
        }
    }
}

// ---------------- node update: CSR gather-sum + conv/residual/lin1/relu ----------------
__global__ void k_node_update(const float* __restrict__ msg_sorted, const int* __restrict__ offsets,
                              const float* __restrict__ cur, const float* __restrict__ h0,
                              const float* __restrict__ conv_bias,
                              const float* __restrict__ lin1_w, const float* __restrict__ lin1_b,
                              float* __restrict__ nxt, int n) {
    __shared__ float t_s[8][HH + 1];
    __shared__ float w_s[HH][HH + 1];
    int t = threadIdx.x;
    for (int i = t; i < HH * HH; i += 256) w_s[i >> 5][i & 31] = lin1_w[i];
    int nl = t >> 5, h = t & 31;
    int nn = blockIdx.x * 8 + nl;
    float tv = 0.f;
    if (nn < n) {
        int s0 = offsets[nn], s1 = offsets[nn + 1];
        float s = 0.f;
        for (int i = s0; i < s1; ++i) s += msg_sorted[(size_t)i * HH + h];
        size_t idx = (size_t)nn * HH + h;
        float conv = s + cur[idx] + conv_bias[h];
        tv = 0.5f * conv + 0.5f * h0[idx];
    }
    t_s[nl][h] = tv;
    __syncthreads();
    if (nn < n) {
        const float BETA = 1.0f / 3.0f;
        float d = lin1_b[h];
        #pragma unroll
        for (int k = 0; k < HH; ++k) d += t_s[nl][k] * w_s[h][k];
        float v = BETA * d + (1.0f - BETA) * tv;
        nxt[(size_t)nn * HH + h] = fmaxf(v, 0.f);
    }
}

// ---------------- BN batch statistics ----------------
__global__ void k_bn_stats(const float* __restrict__ out, float* __restrict__ stats, int n) {
    int t = threadIdx.x;
    int h = t & 31, rg = t >> 5;
    float s = 0.f, s2 = 0.f;
    for (int nn = blockIdx.x * 8 + rg; nn < n; nn += gridDim.x * 8) {
        float v = out[(size_t)nn * HH + h];
        s += v; s2 += v * v;
    }
    __shared__ float sh[256], sh2[256];
    sh[t] = s; sh2[t] = s2;
    __syncthreads();
    if (rg == 0) {
        #pragma unroll
        for (int g = 1; g < 8; ++g) { s += sh[g * 32 + h]; s2 += sh2[g * 32 + h]; }
        atomicAdd(&stats[h], s);
        atomicAdd(&stats[32 + h], s2);
    }
}

// ---------------- BN apply + y_sigmoid head ----------------
__global__ void k_node_out(const float* __restrict__ out, const float* __restrict__ stats,
                           const float* __restrict__ gamma, const float* __restrict__ beta,
                           const float* __restrict__ ylin_w, const float* __restrict__ ylin_b,
                           float* __restrict__ y_bn, float* __restrict__ y_sig, int n) {
    int nn = blockIdx.x * blockDim.x + threadIdx.x;
    if (nn >= n) return;
    float inv_n = 1.f / (float)n;
    float yb[HH];
    #pragma unroll
    for (int h = 0; h < HH; ++h) {
        float mu = stats[h] * inv_n;
        float var = stats[32 + h] * inv_n - mu * mu;
        float v = out[(size_t)nn * HH + h];
        yb[h] = (v - mu) * rsqrtf(var + 1e-5f) * gamma[h] + beta[h];
    }
    #pragma unroll
    for (int h = 0; h < HH; ++h) y_bn[(size_t)nn * HH + h] = yb[h];
    #pragma unroll
    for (int c = 0; c < 3; ++c) {
        float d = ylin_b[c];
        #pragma unroll
        for (int h = 0; h < HH; ++h) d += yb[h] * ylin_w[c * HH + h];
        y_sig[(size_t)nn * 3 + c] = 1.f / (1.f + expf(-d));
    }
}

// ---------------- edge-hop head ----------------
__global__ void k_edge_hop(const float* __restrict__ y_bn, const int* __restrict__ sl,
                           const int* __restrict__ dl, const float* __restrict__ w,
                           const float* __restrict__ b, float* __restrict__ outp, int e2) {
    int e = blockIdx.x * blockDim.x + threadIdx.x;
    if (e >= e2) return;
    const float4* a = (const float4*)(y_bn + (size_t)sl[e] * HH);
    const float4* c = (const float4*)(y_bn + (size_t)dl[e] * HH);
    float d = b[0];
    #pragma unroll
    for (int q = 0; q < 8; ++q) {
        float4 av = a[q], cv = c[q];
        float4 wv = ((const float4*)w)[q];
        d += av.x * cv.x * wv.x + av.y * cv.y * wv.y + av.z * cv.z * wv.z + av.w * cv.w * wv.w;
    }
    outp[e] = 1.f / (1.f + expf(-d));
}

extern "C" void kernel_launch(void* const* d_in, const int* in_sizes, int n_in,
                              void* d_out, int out_size, void* d_ws, size_t ws_size,
                              hipStream_t stream) {
    const float* n_feat   = (const float*)d_in[0];
    const float* e_feat   = (const float*)d_in[1];
    const int*   src      = (const int*)d_in[2];
    const int*   dst      = (const int*)d_in[3];
    const int*   src_list = (const int*)d_in[4];
    const int*   dst_list = (const int*)d_in[5];
    const float* lin0_w   = (const float*)d_in[6];
    const float* lin0_b   = (const float*)d_in[7];
    const float* en1_w    = (const float*)d_in[8];
    const float* en1_b    = (const float*)d_in[9];
    const float* en2_w    = (const float*)d_in[10];
    const float* en2_b    = (const float*)d_in[11];
    const float* conv_bias= (const float*)d_in[12];
    const float* lin1_w   = (const float*)d_in[13];
    const float* lin1_b   = (const float*)d_in[14];
    const float* bn_gamma = (const float*)d_in[15];
    const float* bn_beta  = (const float*)d_in[16];
    const float* ylin_w   = (const float*)d_in[17];
    const float* ylin_b   = (const float*)d_in[18];
    const float* ylin2_w  = (const float*)d_in[19];
    const float* ylin2_b  = (const float*)d_in[20];

    int n  = in_sizes[0] / NODE_IN;
    int E  = in_sizes[1] / EDGE_IN;
    int e2 = in_sizes[4];
    int E_pad = (E + M_TILE - 1) & ~(M_TILE - 1);

    float* ws    = (float*)d_ws;
    size_t nh    = (size_t)n * HH;
    float* out_a = ws;
    float* out_b = out_a + nh;
    float* h0    = out_b + nh;
    float* y_bn  = h0 + nh;
    float* stats = y_bn + nh;                               // 64 floats
    float* msg_sorted = stats + 64;                         // E_pad*32 f32
    unsigned short* W2s = (unsigned short*)(msg_sorted + (size_t)E_pad * HH);  // 1024*128 bf16, swizzled
    unsigned short* Rb  = W2s + 1024 * EDGE_H;              // E_pad*128 bf16
    int* ibase   = (int*)(Rb + (size_t)E_pad * EDGE_H);
    int* deg     = ibase;            // n
    int* offtmp  = deg + n;          // n
    int* bsum    = offtmp + n;       // <=256
    int* offsets = bsum + 256;       // n+1
    int* cursor  = offsets + n + 1;  // n
    int* pos     = cursor + n;       // E_pad (tail garbage; stores guarded)

    int nb = (n + 255) / 256;

    k_prep_w2<<<(1024 * EDGE_H) / 256, 256, 0, stream>>>(en2_w, W2s);
    k_prep_r<<<(E_pad + 255) / 256, 256, 0, stream>>>(e_feat, en1_w, en1_b, Rb, E, E_pad);
    k_lin0<<<(n + 7) / 8, 256, 0, stream>>>(n_feat, lin0_w, lin0_b, out_a, h0, n);

    // CSR by dst
    k_zero_int<<<nb, 256, 0, stream>>>(deg, n);
    k_hist<<<(E + 255) / 256, 256, 0, stream>>>(dst, deg, E);
    k_scan1<<<nb, 256, 0, stream>>>(deg, offtmp, bsum, n);
    k_scan2<<<1, 256, 0, stream>>>(bsum, nb);
    k_scan3<<<(n + 256) / 256, 256, 0, stream>>>(offtmp, bsum, offsets, cursor, n, E);
    k_scatter_pos<<<(E + 255) / 256, 256, 0, stream>>>(dst, offsets, cursor, pos, E);

    const float* cur = out_a;
    float* nxt = out_b;
    for (int s = 0; s < 3; ++s) {
        k_edge_mfma4<<<E_pad / M_TILE, 512, 0, stream>>>(
            Rb, W2s, en2_b, cur, src, pos, msg_sorted, E);
        k_node_update<<<(n + 7) / 8, 256, 0, stream>>>(
            msg_sorted, offsets, cur, h0, conv_bias, lin1_w, lin1_b, nxt, n);
        float* t = (float*)cur; cur = nxt; nxt = t;
    }

    hipMemsetAsync(stats, 0, 64 * sizeof(float), stream);
    k_bn_stats<<<256, 256, 0, stream>>>(cur, stats, n);

    float* y_sig = (float*)d_out;
    float* e_out = y_sig + (size_t)n * 3;
    k_node_out<<<(n + 255) / 256, 256, 0, stream>>>(
        cur, stats, bn_gamma, bn_beta, ylin_w, ylin_b, y_bn, y_sig, n);
    k_edge_hop<<<(e2 + 255) / 256, 256, 0, stream>>>(
        y_bn, src_list, dst_list, ylin2_w, ylin2_b, e_out, e2);
}

// Round 7
// 270.364 us; speedup vs baseline: 2.9589x; 1.1915x over previous
//
#include <hip/hip_runtime.h>
#include <hip/hip_bf16.h>
#include <math.h>

#define HH 32
#define NODE_IN 64
#define EDGE_IN 16
#define EDGE_H 128
#define M_TILE 256   // edges per block in MFMA edge kernel (8 waves x 32 edges)

typedef __attribute__((ext_vector_type(8))) short bf16x8;
typedef __attribute__((ext_vector_type(4))) float f32x4;

__device__ inline unsigned short f2bf(float f) {
    union { float f; unsigned int u; } v; v.f = f;
    unsigned int r = v.u + 0x7fff + ((v.u >> 16) & 1);   // RNE (inputs never NaN)
    return (unsigned short)(r >> 16);
}

__device__ inline void gload_lds16(const void* g, void* lds) {
    __builtin_amdgcn_global_load_lds(
        (const __attribute__((address_space(1))) void*)g,
        (__attribute__((address_space(3))) void*)lds, 16, 0, 0);
}

// ---------------- prep: W2 f32 -> bf16, CHUNK-SWIZZLED global layout ----------------
// W2s[c*128 + p*8 + sub] = bf16(en2_w[c*128 + (p^(c&15))*8 + sub])
// Linear global_load_lds of a 32-col slice lands swizzled in LDS; ds_read_b128
// at chunk (ks*4+lq)^lo is ~2-way bank-conflict (free).
__global__ void k_prep_w2(const float* __restrict__ en2_w, unsigned short* __restrict__ W2s) {
    int i = blockIdx.x * 256 + threadIdx.x;
    int r = i >> 7, q = i & 127;
    int p = q >> 3, sub = q & 7;
    int c = p ^ (r & 15);
    W2s[i] = f2bf(en2_w[r * EDGE_H + c * 8 + sub]);
}

// ---------------- prep: R = relu(e_feat @ en1_w^T + en1_b) -> bf16 [E_pad][128] ----------------
// MFMA version: K=16 zero-padded to 32, no LDS, w1 in B-fragment registers.
// 4 waves x 64 edges = 256 edges/block.
__global__ void __launch_bounds__(256, 4)
k_prep_r(const float* __restrict__ e_feat, const float* __restrict__ en1_w,
         const float* __restrict__ en1_b, unsigned short* __restrict__ Rb,
         int E, int E_pad) {
    int t = threadIdx.x, wave = t >> 6, l = t & 63;
    int lo = l & 15, lq = l >> 4;
    int ebase = blockIdx.x * 256 + wave * 64;

    // B fragments: B[col=j][k] = en1_w[j][k]; k = lq*8+z (real for k<16 -> lq 0,1)
    bf16x8 bfrag[8];
    #pragma unroll
    for (int nt = 0; nt < 8; ++nt) {
        unsigned short br[8] = {0, 0, 0, 0, 0, 0, 0, 0};
        if (lq < 2) {
            const float* wr = en1_w + (nt * 16 + lo) * EDGE_IN + lq * 8;
            #pragma unroll
            for (int z = 0; z < 8; ++z) br[z] = f2bf(wr[z]);
        }
        bfrag[nt] = *(const bf16x8*)br;
    }
    float b1v[8];
    #pragma unroll
    for (int nt = 0; nt < 8; ++nt) b1v[nt] = en1_b[nt * 16 + lo];

    #pragma unroll
    for (int m = 0; m < 4; ++m) {
        int ea = ebase + m * 16 + lo;   // A-row this lane loads
        unsigned short ar[8] = {0, 0, 0, 0, 0, 0, 0, 0};
        if (lq < 2 && ea < E) {
            const float* er = e_feat + (size_t)ea * EDGE_IN + lq * 8;
            float4 v0 = ((const float4*)er)[0];
            float4 v1 = ((const float4*)er)[1];
            ar[0] = f2bf(v0.x); ar[1] = f2bf(v0.y); ar[2] = f2bf(v0.z); ar[3] = f2bf(v0.w);
            ar[4] = f2bf(v1.x); ar[5] = f2bf(v1.y); ar[6] = f2bf(v1.z); ar[7] = f2bf(v1.w);
        }
        bf16x8 af = *(const bf16x8*)ar;

        // D rows this lane OWNS: m*16 + lq*4 + r; col = nt*16 + lo
        int erow = ebase + m * 16 + lq * 4;
        #pragma unroll
        for (int nt = 0; nt < 8; ++nt) {
            f32x4 acc = (f32x4){b1v[nt], b1v[nt], b1v[nt], b1v[nt]};
            acc = __builtin_amdgcn_mfma_f32_16x16x32_bf16(af, bfrag[nt], acc, 0, 0, 0);
            #pragma unroll
            for (int r = 0; r < 4; ++r)
                Rb[(size_t)(erow + r) * EDGE_H + nt * 16 + lo] = f2bf(fmaxf(acc[r], 0.f));
        }
    }
}

// ---------------- lin0 ----------------
__global__ void k_lin0(const float* __restrict__ nf, const float* __restrict__ w,
                       const float* __restrict__ b, float* __restrict__ out,
                       float* __restrict__ h0, int n) {
    __shared__ float nf_s[8][NODE_IN];
    __shared__ float w_s[HH][NODE_IN + 1];
    int t = threadIdx.x;
    for (int i = t; i < HH * NODE_IN; i += 256) w_s[i / NODE_IN][i % NODE_IN] = w[i];
    int n0 = blockIdx.x * 8;
    for (int i = t; i < 8 * NODE_IN; i += 256) {
        int nl = i / NODE_IN, k = i % NODE_IN;
        int nn = n0 + nl;
        nf_s[nl][k] = (nn < n) ? nf[(size_t)nn * NODE_IN + k] : 0.f;
    }
    __syncthreads();
    int nl = t >> 5, h = t & 31;
    int nn = n0 + nl;
    if (nn < n) {
        float acc = b[h];
        #pragma unroll
        for (int k = 0; k < NODE_IN; ++k) acc += nf_s[nl][k] * w_s[h][k];
        acc = fmaxf(acc, 0.f);
        out[(size_t)nn * HH + h] = acc;
        h0[(size_t)nn * HH + h] = acc;
    }
}

// ---------------- CSR build (by dst) ----------------
__global__ void k_zero_int(int* __restrict__ p, int n) {
    int i = blockIdx.x * 256 + threadIdx.x;
    if (i < n) p[i] = 0;
}
__global__ void k_hist(const int* __restrict__ dst, int* __restrict__ deg, int E) {
    int e = blockIdx.x * 256 + threadIdx.x;
    if (e < E) atomicAdd(&deg[dst[e]], 1);
}
__global__ void k_scan1(const int* __restrict__ deg, int* __restrict__ offtmp,
                        int* __restrict__ bsum, int n) {
    __shared__ int sh[256];
    int tid = threadIdx.x;
    int i = blockIdx.x * 256 + tid;
    int v = (i < n) ? deg[i] : 0;
    sh[tid] = v;
    __syncthreads();
    for (int d = 1; d < 256; d <<= 1) {
        int add = (tid >= d) ? sh[tid - d] : 0;
        __syncthreads();
        sh[tid] += add;
        __syncthreads();
    }
    if (i < n) offtmp[i] = sh[tid] - v;
    if (tid == 255) bsum[blockIdx.x] = sh[255];
}
__global__ void k_scan2(int* __restrict__ bsum, int nb) {
    __shared__ int sh[256];
    int tid = threadIdx.x;
    int v = (tid < nb) ? bsum[tid] : 0;
    sh[tid] = v;
    __syncthreads();
    for (int d = 1; d < 256; d <<= 1) {
        int add = (tid >= d) ? sh[tid - d] : 0;
        __syncthreads();
        sh[tid] += add;
        __syncthreads();
    }
    if (tid < nb) bsum[tid] = sh[tid] - v;
}
__global__ void k_scan3(const int* __restrict__ offtmp, const int* __restrict__ bsum,
                        int* __restrict__ offsets, int* __restrict__ cursor, int n, int E) {
    int i = blockIdx.x * 256 + threadIdx.x;
    if (i < n) { offsets[i] = offtmp[i] + bsum[i >> 8]; cursor[i] = 0; }
    if (i == n) offsets[n] = E;
}
__global__ void k_scatter_pos(const int* __restrict__ dst, const int* __restrict__ offsets,
                              int* __restrict__ cursor, int* __restrict__ pos, int E) {
    int e = blockIdx.x * 256 + threadIdx.x;
    if (e < E) pos[e] = offsets[dst[e]] + atomicAdd(&cursor[dst[e]], 1);
}

// ---------------- MFMA edge kernel v4 ----------------
// 8 waves x 32 edges; W2 staged per-h-slice (8KB) in a 4-deep LDS ring via
// global_load_lds; depth-3 prefetch, counted vmcnt(2), raw s_barrier (1/iter).
__global__ void __launch_bounds__(512, 2)
k_edge_mfma4(const unsigned short* __restrict__ Rb, const unsigned short* __restrict__ W2s,
             const float* __restrict__ b2, const float* __restrict__ cur,
             const int* __restrict__ src, const int* __restrict__ pos,
             float* __restrict__ outp, int E) {
    __shared__ unsigned short w2buf[4][32 * EDGE_H];  // 4 x 8KB ring
    __shared__ float x_t[HH][M_TILE];                 // x transposed [h][edge]
    __shared__ float b2_s[HH * HH];
    int t = threadIdx.x, wave = t >> 6, l = t & 63;
    int lo = l & 15, lq = l >> 4;
    int e0 = blockIdx.x * M_TILE;

    for (int i = t; i < HH * HH; i += 512) b2_s[i] = b2[i];

    // gather x[e][:] = cur[src[e]][:], transposed into LDS (8 lanes per edge)
    for (int i = t; i < M_TILE * 8; i += 512) {
        int el = i >> 3, c = i & 7;
        int e = e0 + el;
        float4 v = make_float4(0.f, 0.f, 0.f, 0.f);
        if (e < E) v = ((const float4*)(cur + (size_t)src[e] * HH))[c];
        x_t[c * 4 + 0][el] = v.x; x_t[c * 4 + 1][el] = v.y;
        x_t[c * 4 + 2][el] = v.z; x_t[c * 4 + 3][el] = v.w;
    }

    // A fragments: this wave's 32 edge-rows (2 m-tiles), all K=128
    bf16x8 afrag[2][4];
    #pragma unroll
    for (int m = 0; m < 2; ++m)
        #pragma unroll
        for (int ks = 0; ks < 4; ++ks)
            afrag[m][ks] = *(const bf16x8*)(Rb + (size_t)(e0 + wave * 32 + m * 16 + lo) * EDGE_H + ks * 32 + lq * 8);

    // prologue: stage slices 0,1,2 (1 gload_lds per thread per slice)
    #pragma unroll
    for (int s = 0; s < 3; ++s)
        gload_lds16(W2s + (size_t)s * 4096 + t * 8, &w2buf[s][t * 8]);

    // this wave's x_t/b2 ds_writes must be visible after the first barrier
    asm volatile("s_waitcnt lgkmcnt(0)" ::: "memory");

    float macc[2][2][4];
    #pragma unroll
    for (int m = 0; m < 2; ++m)
        #pragma unroll
        for (int nn = 0; nn < 2; ++nn)
            #pragma unroll
            for (int r = 0; r < 4; ++r) macc[m][nn][r] = 0.f;

    #pragma unroll 4
    for (int h = 0; h < HH; ++h) {
        // wait for slice h (2 newer slices may stay in flight), then sync
        if (h < 30)      asm volatile("s_waitcnt vmcnt(2)" ::: "memory");
        else if (h == 30) asm volatile("s_waitcnt vmcnt(1)" ::: "memory");
        else              asm volatile("s_waitcnt vmcnt(0)" ::: "memory");
        __builtin_amdgcn_s_barrier();
        // everyone is past compute(h-1): safe to overwrite ring slot (h+3)&3
        if (h + 3 < HH)
            gload_lds16(W2s + (size_t)(h + 3) * 4096 + t * 8, &w2buf[(h + 3) & 3][t * 8]);

        const unsigned short* wb = w2buf[h & 3];
        bf16x8 bfrag[2][4];
        #pragma unroll
        for (int nn = 0; nn < 2; ++nn)
            #pragma unroll
            for (int ks = 0; ks < 4; ++ks)
                bfrag[nn][ks] = *(const bf16x8*)&wb[(nn * 16 + lo) * EDGE_H + (((ks * 4 + lq) ^ lo) * 8)];

        f32x4 acc[2][2];
        #pragma unroll
        for (int nn = 0; nn < 2; ++nn) {
            float bb = b2_s[h * HH + nn * 16 + lo];
            acc[0][nn] = (f32x4){bb, bb, bb, bb};
            acc[1][nn] = (f32x4){bb, bb, bb, bb};
        }
        #pragma unroll
        for (int ks = 0; ks < 4; ++ks)
            #pragma unroll
            for (int m = 0; m < 2; ++m)
                #pragma unroll
                for (int nn = 0; nn < 2; ++nn)
                    acc[m][nn] = __builtin_amdgcn_mfma_f32_16x16x32_bf16(
                        afrag[m][ks], bfrag[nn][ks], acc[m][nn], 0, 0, 0);

        #pragma unroll
        for (int m = 0; m < 2; ++m) {
            const float4 xv = *(const float4*)&x_t[h][wave * 32 + m * 16 + lq * 4];
            #pragma unroll
            for (int nn = 0; nn < 2; ++nn) {
                macc[m][nn][0] += xv.x * acc[m][nn][0];
                macc[m][nn][1] += xv.y * acc[m][nn][1];
                macc[m][nn][2] += xv.z * acc[m][nn][2];
                macc[m][nn][3] += xv.w * acc[m][nn][3];
            }
        }
    }

    // store: edge rows wave*32 + m*16 + lq*4 + r, cols nn*16+lo
    #pragma unroll
    for (int m = 0; m < 2; ++m) {
        int ebase = e0 + wave * 32 + m * 16 + lq * 4;
        const int4 p4 = *(const int4*)&pos[ebase];
        int pr[4] = { p4.x, p4.y, p4.z, p4.w };
        #pragma unroll
        for (int r = 0; r < 4; ++r) {
            if (ebase + r < E) {
                outp[(size_t)pr[r] * HH + lo]      = macc[m][0][r];
                outp[(size_t)pr[r] * HH + 16 + lo] = macc[m][1][r];
            }
        }
    }
}

// ---------------- node update: CSR gather-sum + conv/residual/lin1/relu ----------------
__global__ void k_node_update(const float* __restrict__ msg_sorted, const int* __restrict__ offsets,
                              const float* __restrict__ cur, const float* __restrict__ h0,
                              const float* __restrict__ conv_bias,
                              const float* __restrict__ lin1_w, const float* __restrict__ lin1_b,
                              float* __restrict__ nxt, int n) {
    __shared__ float t_s[8][HH + 1];
    __shared__ float w_s[HH][HH + 1];
    int t = threadIdx.x;
    for (int i = t; i < HH * HH; i += 256) w_s[i >> 5][i & 31] = lin1_w[i];
    int nl = t >> 5, h = t & 31;
    int nn = blockIdx.x * 8 + nl;
    float tv = 0.f;
    if (nn < n) {
        int s0 = offsets[nn], s1 = offsets[nn + 1];
        float s = 0.f;
        for (int i = s0; i < s1; ++i) s += msg_sorted[(size_t)i * HH + h];
        size_t idx = (size_t)nn * HH + h;
        float conv = s + cur[idx] + conv_bias[h];
        tv = 0.5f * conv + 0.5f * h0[idx];
    }
    t_s[nl][h] = tv;
    __syncthreads();
    if (nn < n) {
        const float BETA = 1.0f / 3.0f;
        float d = lin1_b[h];
        #pragma unroll
        for (int k = 0; k < HH; ++k) d += t_s[nl][k] * w_s[h][k];
        float v = BETA * d + (1.0f - BETA) * tv;
        nxt[(size_t)nn * HH + h] = fmaxf(v, 0.f);
    }
}

// ---------------- BN batch statistics ----------------
__global__ void k_bn_stats(const float* __restrict__ out, float* __restrict__ stats, int n) {
    int t = threadIdx.x;
    int h = t & 31, rg = t >> 5;
    float s = 0.f, s2 = 0.f;
    for (int nn = blockIdx.x * 8 + rg; nn < n; nn += gridDim.x * 8) {
        float v = out[(size_t)nn * HH + h];
        s += v; s2 += v * v;
    }
    __shared__ float sh[256], sh2[256];
    sh[t] = s; sh2[t] = s2;
    __syncthreads();
    if (rg == 0) {
        #pragma unroll
        for (int g = 1; g < 8; ++g) { s += sh[g * 32 + h]; s2 += sh2[g * 32 + h]; }
        atomicAdd(&stats[h], s);
        atomicAdd(&stats[32 + h], s2);
    }
}

// ---------------- BN apply + y_sigmoid head ----------------
__global__ void k_node_out(const float* __restrict__ out, const float* __restrict__ stats,
                           const float* __restrict__ gamma, const float* __restrict__ beta,
                           const float* __restrict__ ylin_w, const float* __restrict__ ylin_b,
                           float* __restrict__ y_bn, float* __restrict__ y_sig, int n) {
    int nn = blockIdx.x * blockDim.x + threadIdx.x;
    if (nn >= n) return;
    float inv_n = 1.f / (float)n;
    float yb[HH];
    #pragma unroll
    for (int h = 0; h < HH; ++h) {
        float mu = stats[h] * inv_n;
        float var = stats[32 + h] * inv_n - mu * mu;
        float v = out[(size_t)nn * HH + h];
        yb[h] = (v - mu) * rsqrtf(var + 1e-5f) * gamma[h] + beta[h];
    }
    #pragma unroll
    for (int h = 0; h < HH; ++h) y_bn[(size_t)nn * HH + h] = yb[h];
    #pragma unroll
    for (int c = 0; c < 3; ++c) {
        float d = ylin_b[c];
        #pragma unroll
        for (int h = 0; h < HH; ++h) d += yb[h] * ylin_w[c * HH + h];
        y_sig[(size_t)nn * 3 + c] = 1.f / (1.f + expf(-d));
    }
}

// ---------------- edge-hop head ----------------
__global__ void k_edge_hop(const float* __restrict__ y_bn, const int* __restrict__ sl,
                           const int* __restrict__ dl, const float* __restrict__ w,
                           const float* __restrict__ b, float* __restrict__ outp, int e2) {
    int e = blockIdx.x * blockDim.x + threadIdx.x;
    if (e >= e2) return;
    const float4* a = (const float4*)(y_bn + (size_t)sl[e] * HH);
    const float4* c = (const float4*)(y_bn + (size_t)dl[e] * HH);
    float d = b[0];
    #pragma unroll
    for (int q = 0; q < 8; ++q) {
        float4 av = a[q], cv = c[q];
        float4 wv = ((const float4*)w)[q];
        d += av.x * cv.x * wv.x + av.y * cv.y * wv.y + av.z * cv.z * wv.z + av.w * cv.w * wv.w;
    }
    outp[e] = 1.f / (1.f + expf(-d));
}

extern "C" void kernel_launch(void* const* d_in, const int* in_sizes, int n_in,
                              void* d_out, int out_size, void* d_ws, size_t ws_size,
                              hipStream_t stream) {
    const float* n_feat   = (const float*)d_in[0];
    const float* e_feat   = (const float*)d_in[1];
    const int*   src      = (const int*)d_in[2];
    const int*   dst      = (const int*)d_in[3];
    const int*   src_list = (const int*)d_in[4];
    const int*   dst_list = (const int*)d_in[5];
    const float* lin0_w   = (const float*)d_in[6];
    const float* lin0_b   = (const float*)d_in[7];
    const float* en1_w    = (const float*)d_in[8];
    const float* en1_b    = (const float*)d_in[9];
    const float* en2_w    = (const float*)d_in[10];
    const float* en2_b    = (const float*)d_in[11];
    const float* conv_bias= (const float*)d_in[12];
    const float* lin1_w   = (const float*)d_in[13];
    const float* lin1_b   = (const float*)d_in[14];
    const float* bn_gamma = (const float*)d_in[15];
    const float* bn_beta  = (const float*)d_in[16];
    const float* ylin_w   = (const float*)d_in[17];
    const float* ylin_b   = (const float*)d_in[18];
    const float* ylin2_w  = (const float*)d_in[19];
    const float* ylin2_b  = (const float*)d_in[20];

    int n  = in_sizes[0] / NODE_IN;
    int E  = in_sizes[1] / EDGE_IN;
    int e2 = in_sizes[4];
    int E_pad = (E + M_TILE - 1) & ~(M_TILE - 1);

    float* ws    = (float*)d_ws;
    size_t nh    = (size_t)n * HH;
    float* out_a = ws;
    float* out_b = out_a + nh;
    float* h0    = out_b + nh;
    float* y_bn  = h0 + nh;
    float* stats = y_bn + nh;                               // 64 floats
    float* msg_sorted = stats + 64;                         // E_pad*32 f32
    unsigned short* W2s = (unsigned short*)(msg_sorted + (size_t)E_pad * HH);  // 1024*128 bf16, swizzled
    unsigned short* Rb  = W2s + 1024 * EDGE_H;              // E_pad*128 bf16
    int* ibase   = (int*)(Rb + (size_t)E_pad * EDGE_H);
    int* deg     = ibase;            // n
    int* offtmp  = deg + n;          // n
    int* bsum    = offtmp + n;       // <=256
    int* offsets = bsum + 256;       // n+1
    int* cursor  = offsets + n + 1;  // n
    int* pos     = cursor + n;       // E_pad (tail garbage; stores guarded)

    int nb = (n + 255) / 256;

    k_prep_w2<<<(1024 * EDGE_H) / 256, 256, 0, stream>>>(en2_w, W2s);
    k_prep_r<<<E_pad / 256, 256, 0, stream>>>(e_feat, en1_w, en1_b, Rb, E, E_pad);
    k_lin0<<<(n + 7) / 8, 256, 0, stream>>>(n_feat, lin0_w, lin0_b, out_a, h0, n);

    // CSR by dst
    k_zero_int<<<nb, 256, 0, stream>>>(deg, n);
    k_hist<<<(E + 255) / 256, 256, 0, stream>>>(dst, deg, E);
    k_scan1<<<nb, 256, 0, stream>>>(deg, offtmp, bsum, n);
    k_scan2<<<1, 256, 0, stream>>>(bsum, nb);
    k_scan3<<<(n + 256) / 256, 256, 0, stream>>>(offtmp, bsum, offsets, cursor, n, E);
    k_scatter_pos<<<(E + 255) / 256, 256, 0, stream>>>(dst, offsets, cursor, pos, E);

    const float* cur = out_a;
    float* nxt = out_b;
    for (int s = 0; s < 3; ++s) {
        k_edge_mfma4<<<E_pad / M_TILE, 512, 0, stream>>>(
            Rb, W2s, en2_b, cur, src, pos, msg_sorted, E);
        k_node_update<<<(n + 7) / 8, 256, 0, stream>>>(
            msg_sorted, offsets, cur, h0, conv_bias, lin1_w, lin1_b, nxt, n);
        float* t = (float*)cur; cur = nxt; nxt = t;
    }

    hipMemsetAsync(stats, 0, 64 * sizeof(float), stream);
    k_bn_stats<<<256, 256, 0, stream>>>(cur, stats, n);

    float* y_sig = (float*)d_out;
    float* e_out = y_sig + (size_t)n * 3;
    k_node_out<<<(n + 255) / 256, 256, 0, stream>>>(
        cur, stats, bn_gamma, bn_beta, ylin_w, ylin_b, y_bn, y_sig, n);
    k_edge_hop<<<(e2 + 255) / 256, 256, 0, stream>>>(
        y_bn, src_list, dst_list, ylin2_w, ylin2_b, e_out, e2);
}